// Round 8
// baseline (188.048 us; speedup 1.0000x reference)
//
#include <hip/hip_runtime.h>

// Quantized MSA, all-MFMA (f16 exact fixed-point digits).
// R15: qkv/out gload_lds + XOR-swizzled linear LDS — WIN (186.4 -> 180.0).
// R16/R17: attention direct-global K/V — REGRESSION (L1-transaction bound).
// R18: qkv 2-phase BK=32 dbuf — REGRESSION (+6µs, vmcnt(0) drain + 64B segs).
// R19: qkv reverted to R15; out_mfma rebuilt as 32x32 clone — NEUTRAL (181.2,
//   within ±3µs noise of 180.0). Kept (simpler epilogue).
// R20: qkv tile 64x128 -> 128x128 (m93 ladder: +51% at this staging structure).
//   Per k-step 6 ds_read : 8 MFMA (was 4:4); B-panel re-reads halve. Cost:
//   ~190 VGPR (dual-digit 2x2 floatx16 acc), 48KB LDS -> 2 blk/CU
//   (launch_bounds(256,2)). Revert if occupancy loss dominates.
//   attention (R14 dbuf) / out (R19 32x32) / prep unchanged.

#define NTOK 4096      // B*N
#define DIM  768
#define NH   12
#define DH   64
#define SEQ  2048
#define QKVD 2304      // 3*DIM
#define NBH  24        // B*NH
#define LSTR 72        // f16 LDS row stride for attention (144 B rows)
#define KVBUF (64 * LSTR * 2 * 2)   // bytes per K+V staging buffer (18432)

typedef _Float16 half8 __attribute__((ext_vector_type(8)));
typedef _Float16 half4 __attribute__((ext_vector_type(4)));
typedef __fp16   fp16x2 __attribute__((ext_vector_type(2)));
typedef float floatx4 __attribute__((ext_vector_type(4)));
typedef float floatx16 __attribute__((ext_vector_type(16)));

// direct global->LDS DMA, 16B/lane; dest = wave-uniform base + lane*16
#define GLOAD16(gsrc, ldst) \
    __builtin_amdgcn_global_load_lds( \
        (const __attribute__((address_space(1))) void*)(gsrc), \
        (__attribute__((address_space(3))) void*)(ldst), 16, 0, 0)

// ---------------- K0: merged prep (X digit split + weight/bias quant) --------
__global__ __launch_bounds__(256) void prep(
    const float* __restrict__ X,
    const float* __restrict__ wqkv, const float* __restrict__ bqkv,
    const float* __restrict__ wp,   const float* __restrict__ bp,
    _Float16* __restrict__ Xh, _Float16* __restrict__ Xl,
    _Float16* __restrict__ W16, _Float16* __restrict__ Wp16,
    float* __restrict__ bq24, float* __restrict__ bp16)
{
    int i = blockIdx.x * 256 + threadIdx.x;
    int i4 = i * 4;
    if (i4 < NTOK * DIM) {           // X (32,16): clamp unreachable for N(0,1)
        float4 x = *(const float4*)(X + i4);
        float xi[4] = {x.x, x.y, x.z, x.w};
        half4 oh, ol;
#pragma unroll
        for (int j = 0; j < 4; ++j) {
            float v = rintf(xi[j] * 65536.0f);
            float h = rintf(v * (1.0f / 2048.0f));
            ((_Float16*)&oh)[j] = (_Float16)h;
            ((_Float16*)&ol)[j] = (_Float16)(v - 2048.0f * h);
        }
        *(half4*)(Xh + i4) = oh;
        *(half4*)(Xl + i4) = ol;
    }
    if (i4 < QKVD * DIM) {           // w*0.05: |w_int| <~ 70, clamp unreachable
        float4 w = *(const float4*)(wqkv + i4);
        half4 o = {(_Float16)rintf(w.x * 256.0f), (_Float16)rintf(w.y * 256.0f),
                   (_Float16)rintf(w.z * 256.0f), (_Float16)rintf(w.w * 256.0f)};
        *(half4*)(W16 + i4) = o;
    }
    if (i4 < DIM * DIM) {
        float4 w = *(const float4*)(wp + i4);
        half4 o = {(_Float16)rintf(w.x * 256.0f), (_Float16)rintf(w.y * 256.0f),
                   (_Float16)rintf(w.z * 256.0f), (_Float16)rintf(w.w * 256.0f)};
        *(half4*)(Wp16 + i4) = o;
    }
    if (i < QKVD) bq24[i] = rintf(bqkv[i] * 256.0f) * 65536.0f;  // int24 units
    if (i < DIM)  bp16[i] = rintf(bp[i] * 256.0f) * 256.0f;      // int16 units
}

// ---------------- K1: QKV projection, 32x32 MFMA, 128x128 tile --------------
// R15 staging/swizzle geometry, BM doubled. Wave (wr,wc) owns a 64x64 quadrant
// = 2x2 32-tiles x 2 digits (acc 128 VGPR). 48KB LDS, ~2 blk/CU.
__global__ __launch_bounds__(256, 2) void qkv_mfma(
    const _Float16* __restrict__ Xh, const _Float16* __restrict__ Xl,
    const _Float16* __restrict__ W16, const float* __restrict__ bq24,
    _Float16* __restrict__ Q16, _Float16* __restrict__ K16,
    _Float16* __restrict__ Vt16)
{
    __shared__ __align__(16) _Float16 Ah[128 * 64];
    __shared__ __align__(16) _Float16 Al[128 * 64];
    __shared__ __align__(16) _Float16 Bs[128 * 64];
    const int t = threadIdx.x;
    const int w = t >> 6, lane = t & 63;
    const int l31 = lane & 31, hi = lane >> 5;
    const int wr = w >> 1;                // M half (0/1) -> rows 64*wr..+63
    const int wc = w & 1;                 // N half (0/1) -> cols 64*wc..+63
    const int m0 = blockIdx.x * 128;      // token rows (x-fastest: XCD = x%8)
    const int col0 = blockIdx.y * 128;    // output cols

    // staging lane geometry (R15): issue covers 8 rows x 64 cols; lane ->
    // row base + lr, stored granule lane&7 holds logical granule (lane&7)^lr.
    const int lr = lane >> 3;
    const int lg8 = ((lane & 7) ^ lr) * 8;

    floatx16 acch[2][2], accl[2][2];      // [mt][ct] -- constant-indexed
#pragma unroll
    for (int mt = 0; mt < 2; ++mt)
#pragma unroll
        for (int ct = 0; ct < 2; ++ct)
#pragma unroll
            for (int r = 0; r < 16; ++r) { acch[mt][ct][r] = 0.f; accl[mt][ct][r] = 0.f; }

    for (int k0 = 0; k0 < DIM; k0 += 64) {
        __syncthreads();
        // per wave: rows 32w..32w+31 of Ah, Al, Bs (4 issues each = 12 total)
#pragma unroll
        for (int q = 0; q < 4; ++q) {
            GLOAD16(Xh + (size_t)(m0 + 32 * w + 8 * q + lr) * DIM + k0 + lg8,
                    &Ah[(32 * w + 8 * q) * 64]);
            GLOAD16(Xl + (size_t)(m0 + 32 * w + 8 * q + lr) * DIM + k0 + lg8,
                    &Al[(32 * w + 8 * q) * 64]);
            GLOAD16(W16 + (size_t)(col0 + 32 * w + 8 * q + lr) * DIM + k0 + lg8,
                    &Bs[(32 * w + 8 * q) * 64]);
        }
        __syncthreads();
#pragma unroll
        for (int i = 0; i < 4; ++i) {     // k-step of 16
            const int g = 2 * i + hi;
            half8 ah[2], al[2], bf[2];
#pragma unroll
            for (int mt = 0; mt < 2; ++mt) {
                const int arow = 64 * wr + 32 * mt + l31;
                ah[mt] = *(const half8*)(&Ah[arow * 64 + ((g ^ (arow & 7)) << 3)]);
                al[mt] = *(const half8*)(&Al[arow * 64 + ((g ^ (arow & 7)) << 3)]);
            }
#pragma unroll
            for (int ct = 0; ct < 2; ++ct) {
                const int brow = 64 * wc + 32 * ct + l31;
                bf[ct] = *(const half8*)(&Bs[brow * 64 + ((g ^ (brow & 7)) << 3)]);
            }
#pragma unroll
            for (int mt = 0; mt < 2; ++mt)
#pragma unroll
                for (int ct = 0; ct < 2; ++ct) {
                    acch[mt][ct] = __builtin_amdgcn_mfma_f32_32x32x16_f16(ah[mt], bf[ct], acch[mt][ct], 0, 0, 0);
                    accl[mt][ct] = __builtin_amdgcn_mfma_f32_32x32x16_f16(al[mt], bf[ct], accl[mt][ct], 0, 0, 0);
                }
        }
    }

    // epilogue: C rows = token-rel er = (r&3)+8*(r>>2)+4*hi, cols = c-rel l31.
    const int b_ = m0 >> 11;              // m0 multiple of 128; no straddle
#pragma unroll
    for (int ct = 0; ct < 2; ++ct) {
        const int c = col0 + 64 * wc + 32 * ct + l31;
        const int h = c / 192;
        const int jj = c % 192;
        const int kind = jj >> 6;         // 0=Q, 1=K, 2=V (uniform per ct-tile)
        const int e = jj & 63;
        const int bh = b_ * NH + h;
        const float bb = bq24[c];
#pragma unroll
        for (int mt = 0; mt < 2; ++mt) {
            const int nbase = (m0 & 2047) + 64 * wr + 32 * mt;
            float qv[16];
#pragma unroll
            for (int r = 0; r < 16; ++r) {
                float y = (mt == 0)
                    ? fmaf(2048.0f, acch[0][ct][r], accl[0][ct][r]) + bb
                    : fmaf(2048.0f, acch[1][ct][r], accl[1][ct][r]) + bb;
                float q = rintf(y * (1.0f / 65536.0f));
                qv[r] = fminf(fmaxf(q, -32768.0f), 32767.0f);
            }
            if (kind == 2) {
                // sigma (swap bit2<->bit3 within 16-block)
#pragma unroll
                for (int g = 0; g < 4; ++g) {
                    int nv = nbase + 16 * (g >> 1) + 8 * hi + 4 * (g & 1);
                    half4 o = {(_Float16)qv[4 * g + 0], (_Float16)qv[4 * g + 1],
                               (_Float16)qv[4 * g + 2], (_Float16)qv[4 * g + 3]};
                    *(half4*)(Vt16 + ((size_t)bh * DH + e) * SEQ + nv) = o;
                }
            } else {
                _Float16* dst = (kind == 0) ? Q16 : K16;
#pragma unroll
                for (int r = 0; r < 16; ++r) {
                    int er = (r & 3) + 8 * (r >> 2) + 4 * hi;
                    dst[((size_t)bh * SEQ + nbase + er) * DH + e] = (_Float16)qv[r];
                }
            }
        }
    }
}

// ---------------- K2: attention, 32x32 MFMA, dbuf LDS + reg-staged K/V -------
__global__ __launch_bounds__(256, 3) void attention_mfma(
    const _Float16* __restrict__ Q16, const _Float16* __restrict__ K16,
    const _Float16* __restrict__ Vt16,
    _Float16* __restrict__ Zh16, _Float16* __restrict__ Zl16)
{
    // 2 K/V staging buffers (2 x 18432 B); epilogue float scratch (16896 B)
    // overlays buffer 0 after the main loop.
    __shared__ __align__(16) char smem[2 * KVBUF];
    float* scr = (float*)smem;                 // [wj*2+et][er][l31], stride 33

    const int t = threadIdx.x;
    const int bh = blockIdx.x;
    const int qt = blockIdx.y;
    const int w = t >> 6, lane = t & 63;
    const int l31 = lane & 31, hi = lane >> 5;
    const int wj = w & 1;        // q-half
    const int wi = w >> 1;       // m-strip
    const int sr = t >> 3, sk8 = t & 7;   // staging: row 0..31 (+32), col8 0..7
    const _Float16* Qg = Q16 + ((size_t)bh * SEQ + qt * 64) * DH;
    const _Float16* Kg = K16 + (size_t)bh * SEQ * DH;
    const _Float16* Vg = Vt16 + (size_t)bh * DH * SEQ;

    // Q B-frags (whole kernel): B[n=q=l31][k_e = 16i + 8hi + j]
    half8 qf[4];
#pragma unroll
    for (int i = 0; i < 4; ++i)
        qf[i] = *(const half8*)(Qg + (32 * wj + l31) * DH + 16 * i + 8 * hi);

    // prologue: stage tile 0 into buffer 0 (reg round-trip; visibility via
    // the first loop-top barrier)
    half8 pk0, pk1, pv0, pv1;
    pk0 = *(const half8*)(Kg + (size_t)sr * DH + sk8 * 8);
    pk1 = *(const half8*)(Kg + (size_t)(sr + 32) * DH + sk8 * 8);
    pv0 = *(const half8*)(Vg + (size_t)sr * SEQ + sk8 * 8);
    pv1 = *(const half8*)(Vg + (size_t)(sr + 32) * SEQ + sk8 * 8);
    {
        _Float16* Ks = (_Float16*)smem;
        _Float16* Vs = Ks + 64 * LSTR;
        *(half8*)(&Ks[sr * LSTR + sk8 * 8]) = pk0;
        *(half8*)(&Ks[(sr + 32) * LSTR + sk8 * 8]) = pk1;
        *(half8*)(&Vs[sr * LSTR + sk8 * 8]) = pv0;
        *(half8*)(&Vs[(sr + 32) * LSTR + sk8 * 8]) = pv1;
    }

    floatx16 acc0h, acc0l, acc1h, acc1l;   // [et=0/1][digit h/l]; constant-index only
#pragma unroll
    for (int r = 0; r < 16; ++r) { acc0h[r] = 0.f; acc0l[r] = 0.f; acc1h[r] = 0.f; acc1l[r] = 0.f; }

    for (int it = 0; it < 32; ++it) {
        _Float16* Ks = (_Float16*)(smem + (it & 1) * KVBUF);
        _Float16* Vs = Ks + 64 * LSTR;
        // one barrier/iter: makes buf[it&1] writes (end of it-1) visible, and
        // guarantees everyone's reads of buf[(it+1)&1] (iter it-1) are done.
        __syncthreads();

        // T14: issue next tile's global loads now; latency hides under
        // phase1 + quantize + phase2 below. vmcnt drain happens only at the
        // dependent ds_write after the compute.
        if (it < 31) {
            const int mn = (it + 1) * 64;
            pk0 = *(const half8*)(Kg + (size_t)(mn + sr) * DH + sk8 * 8);
            pk1 = *(const half8*)(Kg + (size_t)(mn + sr + 32) * DH + sk8 * 8);
            pv0 = *(const half8*)(Vg + (size_t)sr * SEQ + mn + sk8 * 8);
            pv1 = *(const half8*)(Vg + (size_t)(sr + 32) * SEQ + mn + sk8 * 8);
        }

        // phase 1: S strip = K(strip) . Q^T ; C: lane holds
        // S[m-rel = (r&3)+8*(r>>2)+4hi][q = 32wj + l31], sacc = S_raw * 65536
        floatx16 sc;
#pragma unroll
        for (int r = 0; r < 16; ++r) sc[r] = 0.f;
        __builtin_amdgcn_s_setprio(1);
#pragma unroll
        for (int i = 0; i < 4; ++i) {
            half8 kf = *(const half8*)(&Ks[(32 * wi + l31) * LSTR + 16 * i + 8 * hi]);
            sc = __builtin_amdgcn_mfma_f32_32x32x16_f16(kf, qf[i], sc, 0, 0, 0);
        }
        __builtin_amdgcn_s_setprio(0);

        // quantize (16,8) + digit split in registers
        float hh[16], ll[16];
#pragma unroll
        for (int r = 0; r < 16; ++r) {
            float v = rintf(sc[r] * 0.00390625f);
            v = fminf(fmaxf(v, -32768.0f), 32767.0f);
            float h = rintf(v * (1.0f / 2048.0f));
            hh[r] = h;
            ll[r] = fmaf(-2048.0f, h, v);
        }
        // pack per digit: dw[g] = 2 dwords covering m-rel {8g+4hi+0..3}
        int dwh[4][2], dwl[4][2];
        union { fp16x2 h; int i; } cv;
#pragma unroll
        for (int g = 0; g < 4; ++g) {
            cv.h = __builtin_amdgcn_cvt_pkrtz(hh[4 * g + 0], hh[4 * g + 1]); dwh[g][0] = cv.i;
            cv.h = __builtin_amdgcn_cvt_pkrtz(hh[4 * g + 2], hh[4 * g + 3]); dwh[g][1] = cv.i;
            cv.h = __builtin_amdgcn_cvt_pkrtz(ll[4 * g + 0], ll[4 * g + 1]); dwl[g][0] = cv.i;
            cv.h = __builtin_amdgcn_cvt_pkrtz(ll[4 * g + 2], ll[4 * g + 3]); dwl[g][1] = cv.i;
        }

        // phase 2: A = V^T rows e from LDS (sigma-ordered columns), B = local
        // S dwords (sigma makes required content == lane's own dw[2c],dw[2c+1]).
        half8 vf[2][2];
#pragma unroll
        for (int et = 0; et < 2; ++et)
#pragma unroll
            for (int c = 0; c < 2; ++c)
                vf[et][c] = *(const half8*)(&Vs[(32 * et + l31) * LSTR + 32 * wi + 16 * c + 8 * hi]);
        __builtin_amdgcn_s_setprio(1);
#pragma unroll
        for (int c = 0; c < 2; ++c) {
            union { int b[4]; half8 v; } ubh, ubl;
            ubh.b[0] = dwh[2 * c][0];     ubh.b[1] = dwh[2 * c][1];
            ubh.b[2] = dwh[2 * c + 1][0]; ubh.b[3] = dwh[2 * c + 1][1];
            ubl.b[0] = dwl[2 * c][0];     ubl.b[1] = dwl[2 * c][1];
            ubl.b[2] = dwl[2 * c + 1][0]; ubl.b[3] = dwl[2 * c + 1][1];
            acc0h = __builtin_amdgcn_mfma_f32_32x32x16_f16(vf[0][c], ubh.v, acc0h, 0, 0, 0);
            acc0l = __builtin_amdgcn_mfma_f32_32x32x16_f16(vf[0][c], ubl.v, acc0l, 0, 0, 0);
            acc1h = __builtin_amdgcn_mfma_f32_32x32x16_f16(vf[1][c], ubh.v, acc1h, 0, 0, 0);
            acc1l = __builtin_amdgcn_mfma_f32_32x32x16_f16(vf[1][c], ubl.v, acc1l, 0, 0, 0);
        }
        __builtin_amdgcn_s_setprio(0);

        // write next tile into the other buffer (no barrier needed: nobody
        // reads buf[(it+1)&1] until the next loop-top barrier)
        if (it < 31) {
            _Float16* Kn = (_Float16*)(smem + ((it + 1) & 1) * KVBUF);
            _Float16* Vn = Kn + 64 * LSTR;
            *(half8*)(&Kn[sr * LSTR + sk8 * 8]) = pk0;
            *(half8*)(&Kn[(sr + 32) * LSTR + sk8 * 8]) = pk1;
            *(half8*)(&Vn[sr * LSTR + sk8 * 8]) = pv0;
            *(half8*)(&Vn[(sr + 32) * LSTR + sk8 * 8]) = pv1;
        }
    }

    // epilogue: cross-wave m-reduction. Wave (wi,wj) keeps strip et==wi, sends
    // strip et==1-wi. Elementwise selects -- no dynamic register indexing.
    float zfh[16], zfl[16];
    {
        __syncthreads();
#pragma unroll
        for (int r = 0; r < 16; ++r) {
            int er = (r & 3) + 8 * (r >> 2) + 4 * hi;
            float sendh = wi ? acc0h[r] : acc1h[r];
            scr[((wj * 2 + (1 - wi)) * 32 + er) * 33 + l31] = sendh;
        }
        __syncthreads();
#pragma unroll
        for (int r = 0; r < 16; ++r) {
            int er = (r & 3) + 8 * (r >> 2) + 4 * hi;
            float keeph = wi ? acc1h[r] : acc0h[r];
            zfh[r] = keeph + scr[((wj * 2 + wi) * 32 + er) * 33 + l31];
        }
        __syncthreads();
#pragma unroll
        for (int r = 0; r < 16; ++r) {
            int er = (r & 3) + 8 * (r >> 2) + 4 * hi;
            float sendl = wi ? acc0l[r] : acc1l[r];
            scr[((wj * 2 + (1 - wi)) * 32 + er) * 33 + l31] = sendl;
        }
        __syncthreads();
#pragma unroll
        for (int r = 0; r < 16; ++r) {
            int er = (r & 3) + 8 * (r >> 2) + 4 * hi;
            float keepl = wi ? acc1l[r] : acc0l[r];
            zfl[r] = keepl + scr[((wj * 2 + wi) * 32 + er) * 33 + l31];
        }
    }

    // quantize Z (16,8), split digits, store planes. e = 32wi + er.
    const int b_ = bh / NH, h = bh % NH;
    const int n = qt * 64 + 32 * wj + l31;
    const size_t rowoff = ((size_t)b_ * SEQ + n) * DIM + h * DH;
#pragma unroll
    for (int g = 0; g < 4; ++g) {
        int e0 = 32 * wi + 8 * g + 4 * hi;
        half4 ph, pl;
#pragma unroll
        for (int j = 0; j < 4; ++j) {
            int r = 4 * g + j;
            float zint = fmaf(2048.0f, zfh[r], zfl[r]);  // z_raw*65536
            float zq = rintf(zint * 0.00390625f);
            zq = fminf(fmaxf(zq, -32768.0f), 32767.0f);
            float zdh = rintf(zq * (1.0f / 2048.0f));
            ((_Float16*)&ph)[j] = (_Float16)zdh;
            ((_Float16*)&pl)[j] = (_Float16)(zq - 2048.0f * zdh);
        }
        *(half4*)(Zh16 + rowoff + e0) = ph;
        *(half4*)(Zl16 + rowoff + e0) = pl;
    }
}

// ---------------- K3: output projection, 32x32 MFMA clone of qkv loop -------
__global__ __launch_bounds__(256, 4) void out_mfma(
    const _Float16* __restrict__ Zh, const _Float16* __restrict__ Zl,
    const _Float16* __restrict__ Wp16, const float* __restrict__ bp16,
    float* __restrict__ O)
{
    __shared__ __align__(16) _Float16 Ah[64 * 64];
    __shared__ __align__(16) _Float16 Al[64 * 64];
    __shared__ __align__(16) _Float16 Bs[128 * 64];
    const int t = threadIdx.x;
    const int w = t >> 6, lane = t & 63;
    const int l31 = lane & 31, hi = lane >> 5;
    const int wr = w >> 1;                // row strip (0/1)
    const int wc = w & 1;                 // col half (0/1)
    const int m0 = blockIdx.y * 64;
    const int col0 = blockIdx.x * 128;

    const int lr = lane >> 3;
    const int lg8 = ((lane & 7) ^ lr) * 8;

    floatx16 acch[2], accl[2];
#pragma unroll
    for (int ct = 0; ct < 2; ++ct)
#pragma unroll
        for (int r = 0; r < 16; ++r) { acch[ct][r] = 0.f; accl[ct][r] = 0.f; }

    for (int k0 = 0; k0 < DIM; k0 += 64) {
        __syncthreads();
        GLOAD16(Zh + (size_t)(m0 + 16 * w + lr) * DIM + k0 + lg8,
                &Ah[(2 * w) * 512]);
        GLOAD16(Zh + (size_t)(m0 + 16 * w + 8 + lr) * DIM + k0 + lg8,
                &Ah[(2 * w + 1) * 512]);
        GLOAD16(Zl + (size_t)(m0 + 16 * w + lr) * DIM + k0 + lg8,
                &Al[(2 * w) * 512]);
        GLOAD16(Zl + (size_t)(m0 + 16 * w + 8 + lr) * DIM + k0 + lg8,
                &Al[(2 * w + 1) * 512]);
#pragma unroll
        for (int q = 0; q < 4; ++q) {
            GLOAD16(Wp16 + (size_t)(col0 + 32 * w + 8 * q + lr) * DIM + k0 + lg8,
                    &Bs[(4 * w + q) * 512]);
        }
        __syncthreads();
#pragma unroll
        for (int i = 0; i < 4; ++i) {     // k-step of 16
            const int arow = 32 * wr + l31;
            const int g = 2 * i + hi;
            half8 ah = *(const half8*)(&Ah[arow * 64 + ((g ^ (arow & 7)) << 3)]);
            half8 al = *(const half8*)(&Al[arow * 64 + ((g ^ (arow & 7)) << 3)]);
#pragma unroll
            for (int ct = 0; ct < 2; ++ct) {
                const int brow = 64 * wc + 32 * ct + l31;
                half8 bf = *(const half8*)(&Bs[brow * 64 + ((g ^ (brow & 7)) << 3)]);
                acch[ct] = __builtin_amdgcn_mfma_f32_32x32x16_f16(ah, bf, acch[ct], 0, 0, 0);
                accl[ct] = __builtin_amdgcn_mfma_f32_32x32x16_f16(al, bf, accl[ct], 0, 0, 0);
            }
        }
    }

    // epilogue: C rows = Z-token-rel er = (r&3)+8*(r>>2)+4*hi, cols = l31.
#pragma unroll
    for (int ct = 0; ct < 2; ++ct) {
        const int c = col0 + 64 * wc + 32 * ct + l31;
        const float bb = bp16[c];
#pragma unroll
        for (int r = 0; r < 16; ++r) {
            int er = (r & 3) + 8 * (r >> 2) + 4 * hi;
            float y = fmaf(2048.0f, acch[ct][r], accl[ct][r]) + bb;
            float o = rintf(y * 0.00390625f) * 0.00390625f;
            O[(size_t)(m0 + 32 * wr + er) * DIM + c] = o;
        }
    }
}

extern "C" void kernel_launch(void* const* d_in, const int* in_sizes, int n_in,
                              void* d_out, int out_size, void* d_ws, size_t ws_size,
                              hipStream_t stream) {
    const float* q_in = (const float*)d_in[0];
    const float* wqkv = (const float*)d_in[1];
    const float* bqkv = (const float*)d_in[2];
    const float* wp   = (const float*)d_in[3];
    const float* bp   = (const float*)d_in[4];

    char* w = (char*)d_ws;
    _Float16* W16  = (_Float16*)w;  w += (size_t)QKVD * DIM * 2;
    _Float16* Wp16 = (_Float16*)w;  w += (size_t)DIM * DIM * 2;
    float* bq24    = (float*)w;     w += QKVD * 4;
    float* bp16    = (float*)w;     w += DIM * 4;
    _Float16* Xh   = (_Float16*)w;  w += (size_t)NTOK * DIM * 2;
    _Float16* Xl   = (_Float16*)w;  w += (size_t)NTOK * DIM * 2;
    _Float16* Q16  = (_Float16*)w;  w += (size_t)NBH * SEQ * DH * 2;
    _Float16* K16  = (_Float16*)w;  w += (size_t)NBH * SEQ * DH * 2;
    _Float16* Vt16 = (_Float16*)w;  w += (size_t)NBH * SEQ * DH * 2;
    _Float16* Zh16 = (_Float16*)w;  w += (size_t)NTOK * DIM * 2;
    _Float16* Zl16 = (_Float16*)w;  w += (size_t)NTOK * DIM * 2;
    (void)ws_size; (void)in_sizes; (void)n_in; (void)out_size;

    prep<<<dim3(NTOK * DIM / 4 / 256), 256, 0, stream>>>(
        q_in, wqkv, bqkv, wp, bp, Xh, Xl, W16, Wp16, bq24, bp16);
    qkv_mfma<<<dim3(NTOK / 128, QKVD / 128), 256, 0, stream>>>(
        Xh, Xl, W16, bq24, Q16, K16, Vt16);
    attention_mfma<<<dim3(NBH, SEQ / 64), 256, 0, stream>>>(Q16, K16, Vt16, Zh16, Zl16);
    out_mfma<<<dim3(DIM / 128, NTOK / 64), 256, 0, stream>>>(
        Zh16, Zl16, Wp16, bp16, (float*)d_out);
}

// Round 9
// 183.577 us; speedup vs baseline: 1.0244x; 1.0244x over previous
//
#include <hip/hip_runtime.h>

// Quantized MSA, all-MFMA (f16 exact fixed-point digits).
// R15: qkv/out gload_lds + XOR-swizzled linear LDS — WIN (186.4 -> 180.0).
// R16/R17: attention direct-global K/V — REGRESSION (L1-transaction bound).
// R18: qkv 2-phase BK=32 dbuf — REGRESSION (vmcnt(0)-in-barrier drain).
// R19: out_mfma 32x32 clone — NEUTRAL (181.2). Kept.
// R20: qkv 128x128 tile — REGRESSION (188.0; MfmaUtil 20%, Occ 11.8% at
//   2 blk/CU; also exposed SQ_LDS_BANK_CONFLICT=2.65M: linear 128B rows are
//   an inherent 4-way read conflict; attention's 144B rows measure 0).
// R21: qkv reverted to 64x128 / 4 blk/CU AND switched to 72-half (144B) LDS
//   rows while KEEPING global_load_lds: row = 9 slots of 16B (slot 8 = pad),
//   wave-linear slot s=64j+lane -> row=s/9 (magic mul x7282>>16), granule=s%9
//   (pad refetches granule 0). Wave p stages plane p (w0=Ah,w1=Al,w2/3=Bs).
//   Reads have NO XOR: A[row*72+16i+8hi] (2-way = free, m136).
//   out (R19 32x32) / attention (R14 dbuf) / prep unchanged.

#define NTOK 4096      // B*N
#define DIM  768
#define NH   12
#define DH   64
#define SEQ  2048
#define QKVD 2304      // 3*DIM
#define NBH  24        // B*NH
#define LSTR 72        // f16 LDS row stride: 144 B rows (16B-aligned)
#define KVBUF (64 * LSTR * 2 * 2)   // bytes per K+V staging buffer (18432)

typedef _Float16 half8 __attribute__((ext_vector_type(8)));
typedef _Float16 half4 __attribute__((ext_vector_type(4)));
typedef __fp16   fp16x2 __attribute__((ext_vector_type(2)));
typedef float floatx4 __attribute__((ext_vector_type(4)));
typedef float floatx16 __attribute__((ext_vector_type(16)));

// direct global->LDS DMA, 16B/lane; dest = wave-uniform base + lane*16
#define GLOAD16(gsrc, ldst) \
    __builtin_amdgcn_global_load_lds( \
        (const __attribute__((address_space(1))) void*)(gsrc), \
        (__attribute__((address_space(3))) void*)(ldst), 16, 0, 0)

// ---------------- K0: merged prep (X digit split + weight/bias quant) --------
__global__ __launch_bounds__(256) void prep(
    const float* __restrict__ X,
    const float* __restrict__ wqkv, const float* __restrict__ bqkv,
    const float* __restrict__ wp,   const float* __restrict__ bp,
    _Float16* __restrict__ Xh, _Float16* __restrict__ Xl,
    _Float16* __restrict__ W16, _Float16* __restrict__ Wp16,
    float* __restrict__ bq24, float* __restrict__ bp16)
{
    int i = blockIdx.x * 256 + threadIdx.x;
    int i4 = i * 4;
    if (i4 < NTOK * DIM) {           // X (32,16): clamp unreachable for N(0,1)
        float4 x = *(const float4*)(X + i4);
        float xi[4] = {x.x, x.y, x.z, x.w};
        half4 oh, ol;
#pragma unroll
        for (int j = 0; j < 4; ++j) {
            float v = rintf(xi[j] * 65536.0f);
            float h = rintf(v * (1.0f / 2048.0f));
            ((_Float16*)&oh)[j] = (_Float16)h;
            ((_Float16*)&ol)[j] = (_Float16)(v - 2048.0f * h);
        }
        *(half4*)(Xh + i4) = oh;
        *(half4*)(Xl + i4) = ol;
    }
    if (i4 < QKVD * DIM) {           // w*0.05: |w_int| <~ 70, clamp unreachable
        float4 w = *(const float4*)(wqkv + i4);
        half4 o = {(_Float16)rintf(w.x * 256.0f), (_Float16)rintf(w.y * 256.0f),
                   (_Float16)rintf(w.z * 256.0f), (_Float16)rintf(w.w * 256.0f)};
        *(half4*)(W16 + i4) = o;
    }
    if (i4 < DIM * DIM) {
        float4 w = *(const float4*)(wp + i4);
        half4 o = {(_Float16)rintf(w.x * 256.0f), (_Float16)rintf(w.y * 256.0f),
                   (_Float16)rintf(w.z * 256.0f), (_Float16)rintf(w.w * 256.0f)};
        *(half4*)(Wp16 + i4) = o;
    }
    if (i < QKVD) bq24[i] = rintf(bqkv[i] * 256.0f) * 65536.0f;  // int24 units
    if (i < DIM)  bp16[i] = rintf(bp[i] * 256.0f) * 256.0f;      // int16 units
}

// ---------------- K1: QKV projection, 32x32 MFMA, 64x128 tile, 4 blk/CU ------
// 144B LDS rows + gload_lds staging via div-9 slot mapping; conflict-free reads.
__global__ __launch_bounds__(256, 4) void qkv_mfma(
    const _Float16* __restrict__ Xh, const _Float16* __restrict__ Xl,
    const _Float16* __restrict__ W16, const float* __restrict__ bq24,
    _Float16* __restrict__ Q16, _Float16* __restrict__ K16,
    _Float16* __restrict__ Vt16)
{
    __shared__ __align__(16) _Float16 Ah[64 * LSTR];    //  9216 B
    __shared__ __align__(16) _Float16 Al[64 * LSTR];    //  9216 B
    __shared__ __align__(16) _Float16 Bs[128 * LSTR];   // 18432 B
    const int t = threadIdx.x;
    const int w = t >> 6, lane = t & 63;
    const int l31 = lane & 31, hi = lane >> 5;
    const int wr = w >> 1;                // row strip (0/1)
    const int wc = w & 1;                 // col half (0/1)
    const int m0 = blockIdx.x * 64;       // token rows (x-fastest: XCD = x%8)
    const int col0 = blockIdx.y * 128;    // output cols

    // staging: wave p stages plane p. Slot s = 64j + lane covers LDS bytes
    // s*16; row = s/9, slot-in-row = s%9 (9th slot = 8-half pad, refetch g0).
    const _Float16* gsrc0 = (w == 0) ? Xh + (size_t)m0 * DIM
                          : (w == 1) ? Xl + (size_t)m0 * DIM
                          : W16 + (size_t)(col0 + ((w == 3) ? 64 : 0)) * DIM;
    _Float16* ldst0 = (w == 0) ? Ah : (w == 1) ? Al
                      : Bs + ((w == 3) ? 64 * LSTR : 0);
    int goff[9];                          // per-lane source elem offsets
#pragma unroll
    for (int j = 0; j < 9; ++j) {
        int s = 64 * j + lane;            // 0..575
        int row = (s * 7282) >> 16;       // exact s/9 for s < 32768
        int sl = s - 9 * row;             // 0..8
        goff[j] = row * DIM + ((sl & 7) * 8);   // sl==8 -> granule 0 (pad)
    }

    floatx16 acch[2], accl[2];            // [ct] -- constant indices after unroll
#pragma unroll
    for (int ct = 0; ct < 2; ++ct)
#pragma unroll
        for (int r = 0; r < 16; ++r) { acch[ct][r] = 0.f; accl[ct][r] = 0.f; }

    for (int k0 = 0; k0 < DIM; k0 += 64) {
        __syncthreads();
#pragma unroll
        for (int j = 0; j < 9; ++j)
            GLOAD16(gsrc0 + k0 + goff[j], ldst0 + j * 512);
        __syncthreads();
#pragma unroll
        for (int i = 0; i < 4; ++i) {     // k-step of 16
            const int arow = 32 * wr + l31;
            half8 ah = *(const half8*)(&Ah[arow * LSTR + 16 * i + 8 * hi]);
            half8 al = *(const half8*)(&Al[arow * LSTR + 16 * i + 8 * hi]);
#pragma unroll
            for (int ct = 0; ct < 2; ++ct) {
                const int brow = 64 * wc + 32 * ct + l31;
                half8 bf = *(const half8*)(&Bs[brow * LSTR + 16 * i + 8 * hi]);
                acch[ct] = __builtin_amdgcn_mfma_f32_32x32x16_f16(ah, bf, acch[ct], 0, 0, 0);
                accl[ct] = __builtin_amdgcn_mfma_f32_32x32x16_f16(al, bf, accl[ct], 0, 0, 0);
            }
        }
    }

    // epilogue: C rows = token-rel er = (r&3)+8*(r>>2)+4*hi, cols = c-rel l31.
    const int b_ = m0 >> 11;
    const int nbase = (m0 & 2047) + 32 * wr;
#pragma unroll
    for (int ct = 0; ct < 2; ++ct) {
        const int c = col0 + 64 * wc + 32 * ct + l31;
        const int h = c / 192;
        const int jj = c % 192;
        const int kind = jj >> 6;         // 0=Q, 1=K, 2=V (uniform per ct-tile)
        const int e = jj & 63;
        const int bh = b_ * NH + h;
        const float bb = bq24[c];
        float qv[16];
#pragma unroll
        for (int r = 0; r < 16; ++r) {
            float y = fmaf(2048.0f, acch[ct][r], accl[ct][r]) + bb;
            float q = rintf(y * (1.0f / 65536.0f));
            qv[r] = fminf(fmaxf(q, -32768.0f), 32767.0f);
        }
        if (kind == 2) {
            // sigma (swap bit2<->bit3 within 16-block): er = 8g'+4hi+j maps to
            // 16*(g>>1) + 8*hi + 4*(g&1) + j -- j consecutive -> half4 stores.
#pragma unroll
            for (int g = 0; g < 4; ++g) {
                int nv = nbase + 16 * (g >> 1) + 8 * hi + 4 * (g & 1);
                half4 o = {(_Float16)qv[4 * g + 0], (_Float16)qv[4 * g + 1],
                           (_Float16)qv[4 * g + 2], (_Float16)qv[4 * g + 3]};
                *(half4*)(Vt16 + ((size_t)bh * DH + e) * SEQ + nv) = o;
            }
        } else {
            _Float16* dst = (kind == 0) ? Q16 : K16;
#pragma unroll
            for (int r = 0; r < 16; ++r) {
                int er = (r & 3) + 8 * (r >> 2) + 4 * hi;
                dst[((size_t)bh * SEQ + nbase + er) * DH + e] = (_Float16)qv[r];
            }
        }
    }
}

// ---------------- K2: attention, 32x32 MFMA, dbuf LDS + reg-staged K/V -------
__global__ __launch_bounds__(256, 3) void attention_mfma(
    const _Float16* __restrict__ Q16, const _Float16* __restrict__ K16,
    const _Float16* __restrict__ Vt16,
    _Float16* __restrict__ Zh16, _Float16* __restrict__ Zl16)
{
    // 2 K/V staging buffers (2 x 18432 B); epilogue float scratch (16896 B)
    // overlays buffer 0 after the main loop.
    __shared__ __align__(16) char smem[2 * KVBUF];
    float* scr = (float*)smem;                 // [wj*2+et][er][l31], stride 33

    const int t = threadIdx.x;
    const int bh = blockIdx.x;
    const int qt = blockIdx.y;
    const int w = t >> 6, lane = t & 63;
    const int l31 = lane & 31, hi = lane >> 5;
    const int wj = w & 1;        // q-half
    const int wi = w >> 1;       // m-strip
    const int sr = t >> 3, sk8 = t & 7;   // staging: row 0..31 (+32), col8 0..7
    const _Float16* Qg = Q16 + ((size_t)bh * SEQ + qt * 64) * DH;
    const _Float16* Kg = K16 + (size_t)bh * SEQ * DH;
    const _Float16* Vg = Vt16 + (size_t)bh * DH * SEQ;

    // Q B-frags (whole kernel): B[n=q=l31][k_e = 16i + 8hi + j]
    half8 qf[4];
#pragma unroll
    for (int i = 0; i < 4; ++i)
        qf[i] = *(const half8*)(Qg + (32 * wj + l31) * DH + 16 * i + 8 * hi);

    // prologue: stage tile 0 into buffer 0 (reg round-trip; visibility via
    // the first loop-top barrier)
    half8 pk0, pk1, pv0, pv1;
    pk0 = *(const half8*)(Kg + (size_t)sr * DH + sk8 * 8);
    pk1 = *(const half8*)(Kg + (size_t)(sr + 32) * DH + sk8 * 8);
    pv0 = *(const half8*)(Vg + (size_t)sr * SEQ + sk8 * 8);
    pv1 = *(const half8*)(Vg + (size_t)(sr + 32) * SEQ + sk8 * 8);
    {
        _Float16* Ks = (_Float16*)smem;
        _Float16* Vs = Ks + 64 * LSTR;
        *(half8*)(&Ks[sr * LSTR + sk8 * 8]) = pk0;
        *(half8*)(&Ks[(sr + 32) * LSTR + sk8 * 8]) = pk1;
        *(half8*)(&Vs[sr * LSTR + sk8 * 8]) = pv0;
        *(half8*)(&Vs[(sr + 32) * LSTR + sk8 * 8]) = pv1;
    }

    floatx16 acc0h, acc0l, acc1h, acc1l;   // [et=0/1][digit h/l]; constant-index only
#pragma unroll
    for (int r = 0; r < 16; ++r) { acc0h[r] = 0.f; acc0l[r] = 0.f; acc1h[r] = 0.f; acc1l[r] = 0.f; }

    for (int it = 0; it < 32; ++it) {
        _Float16* Ks = (_Float16*)(smem + (it & 1) * KVBUF);
        _Float16* Vs = Ks + 64 * LSTR;
        // one barrier/iter: makes buf[it&1] writes (end of it-1) visible, and
        // guarantees everyone's reads of buf[(it+1)&1] (iter it-1) are done.
        __syncthreads();

        // T14: issue next tile's global loads now; latency hides under
        // phase1 + quantize + phase2 below. vmcnt drain happens only at the
        // dependent ds_write after the compute.
        if (it < 31) {
            const int mn = (it + 1) * 64;
            pk0 = *(const half8*)(Kg + (size_t)(mn + sr) * DH + sk8 * 8);
            pk1 = *(const half8*)(Kg + (size_t)(mn + sr + 32) * DH + sk8 * 8);
            pv0 = *(const half8*)(Vg + (size_t)sr * SEQ + mn + sk8 * 8);
            pv1 = *(const half8*)(Vg + (size_t)(sr + 32) * SEQ + mn + sk8 * 8);
        }

        // phase 1: S strip = K(strip) . Q^T ; C: lane holds
        // S[m-rel = (r&3)+8*(r>>2)+4hi][q = 32wj + l31], sacc = S_raw * 65536
        floatx16 sc;
#pragma unroll
        for (int r = 0; r < 16; ++r) sc[r] = 0.f;
        __builtin_amdgcn_s_setprio(1);
#pragma unroll
        for (int i = 0; i < 4; ++i) {
            half8 kf = *(const half8*)(&Ks[(32 * wi + l31) * LSTR + 16 * i + 8 * hi]);
            sc = __builtin_amdgcn_mfma_f32_32x32x16_f16(kf, qf[i], sc, 0, 0, 0);
        }
        __builtin_amdgcn_s_setprio(0);

        // quantize (16,8) + digit split in registers
        float hh[16], ll[16];
#pragma unroll
        for (int r = 0; r < 16; ++r) {
            float v = rintf(sc[r] * 0.00390625f);
            v = fminf(fmaxf(v, -32768.0f), 32767.0f);
            float h = rintf(v * (1.0f / 2048.0f));
            hh[r] = h;
            ll[r] = fmaf(-2048.0f, h, v);
        }
        // pack per digit: dw[g] = 2 dwords covering m-rel {8g+4hi+0..3}
        int dwh[4][2], dwl[4][2];
        union { fp16x2 h; int i; } cv;
#pragma unroll
        for (int g = 0; g < 4; ++g) {
            cv.h = __builtin_amdgcn_cvt_pkrtz(hh[4 * g + 0], hh[4 * g + 1]); dwh[g][0] = cv.i;
            cv.h = __builtin_amdgcn_cvt_pkrtz(hh[4 * g + 2], hh[4 * g + 3]); dwh[g][1] = cv.i;
            cv.h = __builtin_amdgcn_cvt_pkrtz(ll[4 * g + 0], ll[4 * g + 1]); dwl[g][0] = cv.i;
            cv.h = __builtin_amdgcn_cvt_pkrtz(ll[4 * g + 2], ll[4 * g + 3]); dwl[g][1] = cv.i;
        }

        // phase 2: A = V^T rows e from LDS (sigma-ordered columns), B = local
        // S dwords (sigma makes required content == lane's own dw[2c],dw[2c+1]).
        half8 vf[2][2];
#pragma unroll
        for (int et = 0; et < 2; ++et)
#pragma unroll
            for (int c = 0; c < 2; ++c)
                vf[et][c] = *(const half8*)(&Vs[(32 * et + l31) * LSTR + 32 * wi + 16 * c + 8 * hi]);
        __builtin_amdgcn_s_setprio(1);
#pragma unroll
        for (int c = 0; c < 2; ++c) {
            union { int b[4]; half8 v; } ubh, ubl;
            ubh.b[0] = dwh[2 * c][0];     ubh.b[1] = dwh[2 * c][1];
            ubh.b[2] = dwh[2 * c + 1][0]; ubh.b[3] = dwh[2 * c + 1][1];
            ubl.b[0] = dwl[2 * c][0];     ubl.b[1] = dwl[2 * c][1];
            ubl.b[2] = dwl[2 * c + 1][0]; ubl.b[3] = dwl[2 * c + 1][1];
            acc0h = __builtin_amdgcn_mfma_f32_32x32x16_f16(vf[0][c], ubh.v, acc0h, 0, 0, 0);
            acc0l = __builtin_amdgcn_mfma_f32_32x32x16_f16(vf[0][c], ubl.v, acc0l, 0, 0, 0);
            acc1h = __builtin_amdgcn_mfma_f32_32x32x16_f16(vf[1][c], ubh.v, acc1h, 0, 0, 0);
            acc1l = __builtin_amdgcn_mfma_f32_32x32x16_f16(vf[1][c], ubl.v, acc1l, 0, 0, 0);
        }
        __builtin_amdgcn_s_setprio(0);

        // write next tile into the other buffer (no barrier needed: nobody
        // reads buf[(it+1)&1] until the next loop-top barrier)
        if (it < 31) {
            _Float16* Kn = (_Float16*)(smem + ((it + 1) & 1) * KVBUF);
            _Float16* Vn = Kn + 64 * LSTR;
            *(half8*)(&Kn[sr * LSTR + sk8 * 8]) = pk0;
            *(half8*)(&Kn[(sr + 32) * LSTR + sk8 * 8]) = pk1;
            *(half8*)(&Vn[sr * LSTR + sk8 * 8]) = pv0;
            *(half8*)(&Vn[(sr + 32) * LSTR + sk8 * 8]) = pv1;
        }
    }

    // epilogue: cross-wave m-reduction. Wave (wi,wj) keeps strip et==wi, sends
    // strip et==1-wi. Elementwise selects -- no dynamic register indexing.
    float zfh[16], zfl[16];
    {
        __syncthreads();
#pragma unroll
        for (int r = 0; r < 16; ++r) {
            int er = (r & 3) + 8 * (r >> 2) + 4 * hi;
            float sendh = wi ? acc0h[r] : acc1h[r];
            scr[((wj * 2 + (1 - wi)) * 32 + er) * 33 + l31] = sendh;
        }
        __syncthreads();
#pragma unroll
        for (int r = 0; r < 16; ++r) {
            int er = (r & 3) + 8 * (r >> 2) + 4 * hi;
            float keeph = wi ? acc1h[r] : acc0h[r];
            zfh[r] = keeph + scr[((wj * 2 + wi) * 32 + er) * 33 + l31];
        }
        __syncthreads();
#pragma unroll
        for (int r = 0; r < 16; ++r) {
            int er = (r & 3) + 8 * (r >> 2) + 4 * hi;
            float sendl = wi ? acc0l[r] : acc1l[r];
            scr[((wj * 2 + (1 - wi)) * 32 + er) * 33 + l31] = sendl;
        }
        __syncthreads();
#pragma unroll
        for (int r = 0; r < 16; ++r) {
            int er = (r & 3) + 8 * (r >> 2) + 4 * hi;
            float keepl = wi ? acc1l[r] : acc0l[r];
            zfl[r] = keepl + scr[((wj * 2 + wi) * 32 + er) * 33 + l31];
        }
    }

    // quantize Z (16,8), split digits, store planes. e = 32wi + er.
    const int b_ = bh / NH, h = bh % NH;
    const int n = qt * 64 + 32 * wj + l31;
    const size_t rowoff = ((size_t)b_ * SEQ + n) * DIM + h * DH;
#pragma unroll
    for (int g = 0; g < 4; ++g) {
        int e0 = 32 * wi + 8 * g + 4 * hi;
        half4 ph, pl;
#pragma unroll
        for (int j = 0; j < 4; ++j) {
            int r = 4 * g + j;
            float zint = fmaf(2048.0f, zfh[r], zfl[r]);  // z_raw*65536
            float zq = rintf(zint * 0.00390625f);
            zq = fminf(fmaxf(zq, -32768.0f), 32767.0f);
            float zdh = rintf(zq * (1.0f / 2048.0f));
            ((_Float16*)&ph)[j] = (_Float16)zdh;
            ((_Float16*)&pl)[j] = (_Float16)(zq - 2048.0f * zdh);
        }
        *(half4*)(Zh16 + rowoff + e0) = ph;
        *(half4*)(Zl16 + rowoff + e0) = pl;
    }
}

// ---------------- K3: output projection, 32x32 MFMA clone (R19) -------------
__global__ __launch_bounds__(256, 4) void out_mfma(
    const _Float16* __restrict__ Zh, const _Float16* __restrict__ Zl,
    const _Float16* __restrict__ Wp16, const float* __restrict__ bp16,
    float* __restrict__ O)
{
    __shared__ __align__(16) _Float16 Ah[64 * 64];
    __shared__ __align__(16) _Float16 Al[64 * 64];
    __shared__ __align__(16) _Float16 Bs[128 * 64];
    const int t = threadIdx.x;
    const int w = t >> 6, lane = t & 63;
    const int l31 = lane & 31, hi = lane >> 5;
    const int wr = w >> 1;                // row strip (0/1)
    const int wc = w & 1;                 // col half (0/1)
    const int m0 = blockIdx.y * 64;
    const int col0 = blockIdx.x * 128;

    const int lr = lane >> 3;
    const int lg8 = ((lane & 7) ^ lr) * 8;

    floatx16 acch[2], accl[2];
#pragma unroll
    for (int ct = 0; ct < 2; ++ct)
#pragma unroll
        for (int r = 0; r < 16; ++r) { acch[ct][r] = 0.f; accl[ct][r] = 0.f; }

    for (int k0 = 0; k0 < DIM; k0 += 64) {
        __syncthreads();
        GLOAD16(Zh + (size_t)(m0 + 16 * w + lr) * DIM + k0 + lg8,
                &Ah[(2 * w) * 512]);
        GLOAD16(Zh + (size_t)(m0 + 16 * w + 8 + lr) * DIM + k0 + lg8,
                &Ah[(2 * w + 1) * 512]);
        GLOAD16(Zl + (size_t)(m0 + 16 * w + lr) * DIM + k0 + lg8,
                &Al[(2 * w) * 512]);
        GLOAD16(Zl + (size_t)(m0 + 16 * w + 8 + lr) * DIM + k0 + lg8,
                &Al[(2 * w + 1) * 512]);
#pragma unroll
        for (int q = 0; q < 4; ++q) {
            GLOAD16(Wp16 + (size_t)(col0 + 32 * w + 8 * q + lr) * DIM + k0 + lg8,
                    &Bs[(4 * w + q) * 512]);
        }
        __syncthreads();
#pragma unroll
        for (int i = 0; i < 4; ++i) {     // k-step of 16
            const int arow = 32 * wr + l31;
            const int g = 2 * i + hi;
            half8 ah = *(const half8*)(&Ah[arow * 64 + ((g ^ (arow & 7)) << 3)]);
            half8 al = *(const half8*)(&Al[arow * 64 + ((g ^ (arow & 7)) << 3)]);
#pragma unroll
            for (int ct = 0; ct < 2; ++ct) {
                const int brow = 64 * wc + 32 * ct + l31;
                half8 bf = *(const half8*)(&Bs[brow * 64 + ((g ^ (brow & 7)) << 3)]);
                acch[ct] = __builtin_amdgcn_mfma_f32_32x32x16_f16(ah, bf, acch[ct], 0, 0, 0);
                accl[ct] = __builtin_amdgcn_mfma_f32_32x32x16_f16(al, bf, accl[ct], 0, 0, 0);
            }
        }
    }

    // epilogue: C rows = Z-token-rel er = (r&3)+8*(r>>2)+4*hi, cols = l31.
#pragma unroll
    for (int ct = 0; ct < 2; ++ct) {
        const int c = col0 + 64 * wc + 32 * ct + l31;
        const float bb = bp16[c];
#pragma unroll
        for (int r = 0; r < 16; ++r) {
            int er = (r & 3) + 8 * (r >> 2) + 4 * hi;
            float y = fmaf(2048.0f, acch[ct][r], accl[ct][r]) + bb;
            float o = rintf(y * 0.00390625f) * 0.00390625f;
            O[(size_t)(m0 + 32 * wr + er) * DIM + c] = o;
        }
    }
}

extern "C" void kernel_launch(void* const* d_in, const int* in_sizes, int n_in,
                              void* d_out, int out_size, void* d_ws, size_t ws_size,
                              hipStream_t stream) {
    const float* q_in = (const float*)d_in[0];
    const float* wqkv = (const float*)d_in[1];
    const float* bqkv = (const float*)d_in[2];
    const float* wp   = (const float*)d_in[3];
    const float* bp   = (const float*)d_in[4];

    char* w = (char*)d_ws;
    _Float16* W16  = (_Float16*)w;  w += (size_t)QKVD * DIM * 2;
    _Float16* Wp16 = (_Float16*)w;  w += (size_t)DIM * DIM * 2;
    float* bq24    = (float*)w;     w += QKVD * 4;
    float* bp16    = (float*)w;     w += DIM * 4;
    _Float16* Xh   = (_Float16*)w;  w += (size_t)NTOK * DIM * 2;
    _Float16* Xl   = (_Float16*)w;  w += (size_t)NTOK * DIM * 2;
    _Float16* Q16  = (_Float16*)w;  w += (size_t)NBH * SEQ * DH * 2;
    _Float16* K16  = (_Float16*)w;  w += (size_t)NBH * SEQ * DH * 2;
    _Float16* Vt16 = (_Float16*)w;  w += (size_t)NBH * SEQ * DH * 2;
    _Float16* Zh16 = (_Float16*)w;  w += (size_t)NTOK * DIM * 2;
    _Float16* Zl16 = (_Float16*)w;  w += (size_t)NTOK * DIM * 2;
    (void)ws_size; (void)in_sizes; (void)n_in; (void)out_size;

    prep<<<dim3(NTOK * DIM / 4 / 256), 256, 0, stream>>>(
        q_in, wqkv, bqkv, wp, bp, Xh, Xl, W16, Wp16, bq24, bp16);
    qkv_mfma<<<dim3(NTOK / 64, QKVD / 128), 256, 0, stream>>>(
        Xh, Xl, W16, bq24, Q16, K16, Vt16);
    attention_mfma<<<dim3(NBH, SEQ / 64), 256, 0, stream>>>(Q16, K16, Vt16, Zh16, Zl16);
    out_mfma<<<dim3(DIM / 128, NTOK / 64), 256, 0, stream>>>(
        Zh16, Zl16, Wp16, bp16, (float*)d_out);
}

// Round 10
// 182.006 us; speedup vs baseline: 1.0332x; 1.0086x over previous
//
#include <hip/hip_runtime.h>

// Quantized MSA, all-MFMA (f16 exact fixed-point digits).
// R15: qkv/out gload_lds + XOR-swizzled linear LDS — WIN (186.4 -> 180.0).
// R16/R17: attention direct-global K/V — REGRESSION (L1-transaction bound).
// R18: qkv 2-phase BK=32 dbuf — REGRESSION (vmcnt(0)-in-barrier drain).
// R19: out_mfma 32x32 clone — NEUTRAL (181.2). R20: qkv 128x128 — REGRESSION
//   (occupancy 2/CU; exposed 2.65M LDS conflicts in linear-64 rows).
// R21: qkv 144B rows + div-9 gload_lds — NEUTRAL (183.6; run ~3% warm —
//   unchanged attention read 52.7 vs 50.9). Kept (conflict-free by design).
// R22: out_mfma tile 64x128 -> 64x64. out's grid was 384 blocks = 1.5 blk/CU
//   (residency model: out per-block work == qkv per-block work, so out's
//   duration was ~T_b ~ 40µs, latency-exposed). Now grid (12,64)=768 = 3/CU,
//   LDS 24.6KB, single-ct waves. qkv/attention/prep byte-identical to R21.

#define NTOK 4096      // B*N
#define DIM  768
#define NH   12
#define DH   64
#define SEQ  2048
#define QKVD 2304      // 3*DIM
#define NBH  24        // B*NH
#define LSTR 72        // f16 LDS row stride: 144 B rows (16B-aligned)
#define KVBUF (64 * LSTR * 2 * 2)   // bytes per K+V staging buffer (18432)

typedef _Float16 half8 __attribute__((ext_vector_type(8)));
typedef _Float16 half4 __attribute__((ext_vector_type(4)));
typedef __fp16   fp16x2 __attribute__((ext_vector_type(2)));
typedef float floatx4 __attribute__((ext_vector_type(4)));
typedef float floatx16 __attribute__((ext_vector_type(16)));

// direct global->LDS DMA, 16B/lane; dest = wave-uniform base + lane*16
#define GLOAD16(gsrc, ldst) \
    __builtin_amdgcn_global_load_lds( \
        (const __attribute__((address_space(1))) void*)(gsrc), \
        (__attribute__((address_space(3))) void*)(ldst), 16, 0, 0)

// ---------------- K0: merged prep (X digit split + weight/bias quant) --------
__global__ __launch_bounds__(256) void prep(
    const float* __restrict__ X,
    const float* __restrict__ wqkv, const float* __restrict__ bqkv,
    const float* __restrict__ wp,   const float* __restrict__ bp,
    _Float16* __restrict__ Xh, _Float16* __restrict__ Xl,
    _Float16* __restrict__ W16, _Float16* __restrict__ Wp16,
    float* __restrict__ bq24, float* __restrict__ bp16)
{
    int i = blockIdx.x * 256 + threadIdx.x;
    int i4 = i * 4;
    if (i4 < NTOK * DIM) {           // X (32,16): clamp unreachable for N(0,1)
        float4 x = *(const float4*)(X + i4);
        float xi[4] = {x.x, x.y, x.z, x.w};
        half4 oh, ol;
#pragma unroll
        for (int j = 0; j < 4; ++j) {
            float v = rintf(xi[j] * 65536.0f);
            float h = rintf(v * (1.0f / 2048.0f));
            ((_Float16*)&oh)[j] = (_Float16)h;
            ((_Float16*)&ol)[j] = (_Float16)(v - 2048.0f * h);
        }
        *(half4*)(Xh + i4) = oh;
        *(half4*)(Xl + i4) = ol;
    }
    if (i4 < QKVD * DIM) {           // w*0.05: |w_int| <~ 70, clamp unreachable
        float4 w = *(const float4*)(wqkv + i4);
        half4 o = {(_Float16)rintf(w.x * 256.0f), (_Float16)rintf(w.y * 256.0f),
                   (_Float16)rintf(w.z * 256.0f), (_Float16)rintf(w.w * 256.0f)};
        *(half4*)(W16 + i4) = o;
    }
    if (i4 < DIM * DIM) {
        float4 w = *(const float4*)(wp + i4);
        half4 o = {(_Float16)rintf(w.x * 256.0f), (_Float16)rintf(w.y * 256.0f),
                   (_Float16)rintf(w.z * 256.0f), (_Float16)rintf(w.w * 256.0f)};
        *(half4*)(Wp16 + i4) = o;
    }
    if (i < QKVD) bq24[i] = rintf(bqkv[i] * 256.0f) * 65536.0f;  // int24 units
    if (i < DIM)  bp16[i] = rintf(bp[i] * 256.0f) * 256.0f;      // int16 units
}

// ---------------- K1: QKV projection, 32x32 MFMA, 64x128 tile, 4 blk/CU ------
// 144B LDS rows + gload_lds staging via div-9 slot mapping; conflict-free reads.
__global__ __launch_bounds__(256, 4) void qkv_mfma(
    const _Float16* __restrict__ Xh, const _Float16* __restrict__ Xl,
    const _Float16* __restrict__ W16, const float* __restrict__ bq24,
    _Float16* __restrict__ Q16, _Float16* __restrict__ K16,
    _Float16* __restrict__ Vt16)
{
    __shared__ __align__(16) _Float16 Ah[64 * LSTR];    //  9216 B
    __shared__ __align__(16) _Float16 Al[64 * LSTR];    //  9216 B
    __shared__ __align__(16) _Float16 Bs[128 * LSTR];   // 18432 B
    const int t = threadIdx.x;
    const int w = t >> 6, lane = t & 63;
    const int l31 = lane & 31, hi = lane >> 5;
    const int wr = w >> 1;                // row strip (0/1)
    const int wc = w & 1;                 // col half (0/1)
    const int m0 = blockIdx.x * 64;       // token rows (x-fastest: XCD = x%8)
    const int col0 = blockIdx.y * 128;    // output cols

    // staging: wave p stages plane p. Slot s = 64j + lane covers LDS bytes
    // s*16; row = s/9, slot-in-row = s%9 (9th slot = 8-half pad, refetch g0).
    const _Float16* gsrc0 = (w == 0) ? Xh + (size_t)m0 * DIM
                          : (w == 1) ? Xl + (size_t)m0 * DIM
                          : W16 + (size_t)(col0 + ((w == 3) ? 64 : 0)) * DIM;
    _Float16* ldst0 = (w == 0) ? Ah : (w == 1) ? Al
                      : Bs + ((w == 3) ? 64 * LSTR : 0);
    int goff[9];                          // per-lane source elem offsets
#pragma unroll
    for (int j = 0; j < 9; ++j) {
        int s = 64 * j + lane;            // 0..575
        int row = (s * 7282) >> 16;       // exact s/9 for s < 32768
        int sl = s - 9 * row;             // 0..8
        goff[j] = row * DIM + ((sl & 7) * 8);   // sl==8 -> granule 0 (pad)
    }

    floatx16 acch[2], accl[2];            // [ct] -- constant indices after unroll
#pragma unroll
    for (int ct = 0; ct < 2; ++ct)
#pragma unroll
        for (int r = 0; r < 16; ++r) { acch[ct][r] = 0.f; accl[ct][r] = 0.f; }

    for (int k0 = 0; k0 < DIM; k0 += 64) {
        __syncthreads();
#pragma unroll
        for (int j = 0; j < 9; ++j)
            GLOAD16(gsrc0 + k0 + goff[j], ldst0 + j * 512);
        __syncthreads();
#pragma unroll
        for (int i = 0; i < 4; ++i) {     // k-step of 16
            const int arow = 32 * wr + l31;
            half8 ah = *(const half8*)(&Ah[arow * LSTR + 16 * i + 8 * hi]);
            half8 al = *(const half8*)(&Al[arow * LSTR + 16 * i + 8 * hi]);
#pragma unroll
            for (int ct = 0; ct < 2; ++ct) {
                const int brow = 64 * wc + 32 * ct + l31;
                half8 bf = *(const half8*)(&Bs[brow * LSTR + 16 * i + 8 * hi]);
                acch[ct] = __builtin_amdgcn_mfma_f32_32x32x16_f16(ah, bf, acch[ct], 0, 0, 0);
                accl[ct] = __builtin_amdgcn_mfma_f32_32x32x16_f16(al, bf, accl[ct], 0, 0, 0);
            }
        }
    }

    // epilogue: C rows = token-rel er = (r&3)+8*(r>>2)+4*hi, cols = c-rel l31.
    const int b_ = m0 >> 11;
    const int nbase = (m0 & 2047) + 32 * wr;
#pragma unroll
    for (int ct = 0; ct < 2; ++ct) {
        const int c = col0 + 64 * wc + 32 * ct + l31;
        const int h = c / 192;
        const int jj = c % 192;
        const int kind = jj >> 6;         // 0=Q, 1=K, 2=V (uniform per ct-tile)
        const int e = jj & 63;
        const int bh = b_ * NH + h;
        const float bb = bq24[c];
        float qv[16];
#pragma unroll
        for (int r = 0; r < 16; ++r) {
            float y = fmaf(2048.0f, acch[ct][r], accl[ct][r]) + bb;
            float q = rintf(y * (1.0f / 65536.0f));
            qv[r] = fminf(fmaxf(q, -32768.0f), 32767.0f);
        }
        if (kind == 2) {
            // sigma (swap bit2<->bit3 within 16-block): er = 8g'+4hi+j maps to
            // 16*(g>>1) + 8*hi + 4*(g&1) + j -- j consecutive -> half4 stores.
#pragma unroll
            for (int g = 0; g < 4; ++g) {
                int nv = nbase + 16 * (g >> 1) + 8 * hi + 4 * (g & 1);
                half4 o = {(_Float16)qv[4 * g + 0], (_Float16)qv[4 * g + 1],
                           (_Float16)qv[4 * g + 2], (_Float16)qv[4 * g + 3]};
                *(half4*)(Vt16 + ((size_t)bh * DH + e) * SEQ + nv) = o;
            }
        } else {
            _Float16* dst = (kind == 0) ? Q16 : K16;
#pragma unroll
            for (int r = 0; r < 16; ++r) {
                int er = (r & 3) + 8 * (r >> 2) + 4 * hi;
                dst[((size_t)bh * SEQ + nbase + er) * DH + e] = (_Float16)qv[r];
            }
        }
    }
}

// ---------------- K2: attention, 32x32 MFMA, dbuf LDS + reg-staged K/V -------
__global__ __launch_bounds__(256, 3) void attention_mfma(
    const _Float16* __restrict__ Q16, const _Float16* __restrict__ K16,
    const _Float16* __restrict__ Vt16,
    _Float16* __restrict__ Zh16, _Float16* __restrict__ Zl16)
{
    // 2 K/V staging buffers (2 x 18432 B); epilogue float scratch (16896 B)
    // overlays buffer 0 after the main loop.
    __shared__ __align__(16) char smem[2 * KVBUF];
    float* scr = (float*)smem;                 // [wj*2+et][er][l31], stride 33

    const int t = threadIdx.x;
    const int bh = blockIdx.x;
    const int qt = blockIdx.y;
    const int w = t >> 6, lane = t & 63;
    const int l31 = lane & 31, hi = lane >> 5;
    const int wj = w & 1;        // q-half
    const int wi = w >> 1;       // m-strip
    const int sr = t >> 3, sk8 = t & 7;   // staging: row 0..31 (+32), col8 0..7
    const _Float16* Qg = Q16 + ((size_t)bh * SEQ + qt * 64) * DH;
    const _Float16* Kg = K16 + (size_t)bh * SEQ * DH;
    const _Float16* Vg = Vt16 + (size_t)bh * DH * SEQ;

    // Q B-frags (whole kernel): B[n=q=l31][k_e = 16i + 8hi + j]
    half8 qf[4];
#pragma unroll
    for (int i = 0; i < 4; ++i)
        qf[i] = *(const half8*)(Qg + (32 * wj + l31) * DH + 16 * i + 8 * hi);

    // prologue: stage tile 0 into buffer 0 (reg round-trip; visibility via
    // the first loop-top barrier)
    half8 pk0, pk1, pv0, pv1;
    pk0 = *(const half8*)(Kg + (size_t)sr * DH + sk8 * 8);
    pk1 = *(const half8*)(Kg + (size_t)(sr + 32) * DH + sk8 * 8);
    pv0 = *(const half8*)(Vg + (size_t)sr * SEQ + sk8 * 8);
    pv1 = *(const half8*)(Vg + (size_t)(sr + 32) * SEQ + sk8 * 8);
    {
        _Float16* Ks = (_Float16*)smem;
        _Float16* Vs = Ks + 64 * LSTR;
        *(half8*)(&Ks[sr * LSTR + sk8 * 8]) = pk0;
        *(half8*)(&Ks[(sr + 32) * LSTR + sk8 * 8]) = pk1;
        *(half8*)(&Vs[sr * LSTR + sk8 * 8]) = pv0;
        *(half8*)(&Vs[(sr + 32) * LSTR + sk8 * 8]) = pv1;
    }

    floatx16 acc0h, acc0l, acc1h, acc1l;   // [et=0/1][digit h/l]; constant-index only
#pragma unroll
    for (int r = 0; r < 16; ++r) { acc0h[r] = 0.f; acc0l[r] = 0.f; acc1h[r] = 0.f; acc1l[r] = 0.f; }

    for (int it = 0; it < 32; ++it) {
        _Float16* Ks = (_Float16*)(smem + (it & 1) * KVBUF);
        _Float16* Vs = Ks + 64 * LSTR;
        // one barrier/iter: makes buf[it&1] writes (end of it-1) visible, and
        // guarantees everyone's reads of buf[(it+1)&1] (iter it-1) are done.
        __syncthreads();

        // T14: issue next tile's global loads now; latency hides under
        // phase1 + quantize + phase2 below. vmcnt drain happens only at the
        // dependent ds_write after the compute.
        if (it < 31) {
            const int mn = (it + 1) * 64;
            pk0 = *(const half8*)(Kg + (size_t)(mn + sr) * DH + sk8 * 8);
            pk1 = *(const half8*)(Kg + (size_t)(mn + sr + 32) * DH + sk8 * 8);
            pv0 = *(const half8*)(Vg + (size_t)sr * SEQ + mn + sk8 * 8);
            pv1 = *(const half8*)(Vg + (size_t)(sr + 32) * SEQ + mn + sk8 * 8);
        }

        // phase 1: S strip = K(strip) . Q^T ; C: lane holds
        // S[m-rel = (r&3)+8*(r>>2)+4hi][q = 32wj + l31], sacc = S_raw * 65536
        floatx16 sc;
#pragma unroll
        for (int r = 0; r < 16; ++r) sc[r] = 0.f;
        __builtin_amdgcn_s_setprio(1);
#pragma unroll
        for (int i = 0; i < 4; ++i) {
            half8 kf = *(const half8*)(&Ks[(32 * wi + l31) * LSTR + 16 * i + 8 * hi]);
            sc = __builtin_amdgcn_mfma_f32_32x32x16_f16(kf, qf[i], sc, 0, 0, 0);
        }
        __builtin_amdgcn_s_setprio(0);

        // quantize (16,8) + digit split in registers
        float hh[16], ll[16];
#pragma unroll
        for (int r = 0; r < 16; ++r) {
            float v = rintf(sc[r] * 0.00390625f);
            v = fminf(fmaxf(v, -32768.0f), 32767.0f);
            float h = rintf(v * (1.0f / 2048.0f));
            hh[r] = h;
            ll[r] = fmaf(-2048.0f, h, v);
        }
        // pack per digit: dw[g] = 2 dwords covering m-rel {8g+4hi+0..3}
        int dwh[4][2], dwl[4][2];
        union { fp16x2 h; int i; } cv;
#pragma unroll
        for (int g = 0; g < 4; ++g) {
            cv.h = __builtin_amdgcn_cvt_pkrtz(hh[4 * g + 0], hh[4 * g + 1]); dwh[g][0] = cv.i;
            cv.h = __builtin_amdgcn_cvt_pkrtz(hh[4 * g + 2], hh[4 * g + 3]); dwh[g][1] = cv.i;
            cv.h = __builtin_amdgcn_cvt_pkrtz(ll[4 * g + 0], ll[4 * g + 1]); dwl[g][0] = cv.i;
            cv.h = __builtin_amdgcn_cvt_pkrtz(ll[4 * g + 2], ll[4 * g + 3]); dwl[g][1] = cv.i;
        }

        // phase 2: A = V^T rows e from LDS (sigma-ordered columns), B = local
        // S dwords (sigma makes required content == lane's own dw[2c],dw[2c+1]).
        half8 vf[2][2];
#pragma unroll
        for (int et = 0; et < 2; ++et)
#pragma unroll
            for (int c = 0; c < 2; ++c)
                vf[et][c] = *(const half8*)(&Vs[(32 * et + l31) * LSTR + 32 * wi + 16 * c + 8 * hi]);
        __builtin_amdgcn_s_setprio(1);
#pragma unroll
        for (int c = 0; c < 2; ++c) {
            union { int b[4]; half8 v; } ubh, ubl;
            ubh.b[0] = dwh[2 * c][0];     ubh.b[1] = dwh[2 * c][1];
            ubh.b[2] = dwh[2 * c + 1][0]; ubh.b[3] = dwh[2 * c + 1][1];
            ubl.b[0] = dwl[2 * c][0];     ubl.b[1] = dwl[2 * c][1];
            ubl.b[2] = dwl[2 * c + 1][0]; ubl.b[3] = dwl[2 * c + 1][1];
            acc0h = __builtin_amdgcn_mfma_f32_32x32x16_f16(vf[0][c], ubh.v, acc0h, 0, 0, 0);
            acc0l = __builtin_amdgcn_mfma_f32_32x32x16_f16(vf[0][c], ubl.v, acc0l, 0, 0, 0);
            acc1h = __builtin_amdgcn_mfma_f32_32x32x16_f16(vf[1][c], ubh.v, acc1h, 0, 0, 0);
            acc1l = __builtin_amdgcn_mfma_f32_32x32x16_f16(vf[1][c], ubl.v, acc1l, 0, 0, 0);
        }
        __builtin_amdgcn_s_setprio(0);

        // write next tile into the other buffer (no barrier needed: nobody
        // reads buf[(it+1)&1] until the next loop-top barrier)
        if (it < 31) {
            _Float16* Kn = (_Float16*)(smem + ((it + 1) & 1) * KVBUF);
            _Float16* Vn = Kn + 64 * LSTR;
            *(half8*)(&Kn[sr * LSTR + sk8 * 8]) = pk0;
            *(half8*)(&Kn[(sr + 32) * LSTR + sk8 * 8]) = pk1;
            *(half8*)(&Vn[sr * LSTR + sk8 * 8]) = pv0;
            *(half8*)(&Vn[(sr + 32) * LSTR + sk8 * 8]) = pv1;
        }
    }

    // epilogue: cross-wave m-reduction. Wave (wi,wj) keeps strip et==wi, sends
    // strip et==1-wi. Elementwise selects -- no dynamic register indexing.
    float zfh[16], zfl[16];
    {
        __syncthreads();
#pragma unroll
        for (int r = 0; r < 16; ++r) {
            int er = (r & 3) + 8 * (r >> 2) + 4 * hi;
            float sendh = wi ? acc0h[r] : acc1h[r];
            scr[((wj * 2 + (1 - wi)) * 32 + er) * 33 + l31] = sendh;
        }
        __syncthreads();
#pragma unroll
        for (int r = 0; r < 16; ++r) {
            int er = (r & 3) + 8 * (r >> 2) + 4 * hi;
            float keeph = wi ? acc1h[r] : acc0h[r];
            zfh[r] = keeph + scr[((wj * 2 + wi) * 32 + er) * 33 + l31];
        }
        __syncthreads();
#pragma unroll
        for (int r = 0; r < 16; ++r) {
            int er = (r & 3) + 8 * (r >> 2) + 4 * hi;
            float sendl = wi ? acc0l[r] : acc1l[r];
            scr[((wj * 2 + (1 - wi)) * 32 + er) * 33 + l31] = sendl;
        }
        __syncthreads();
#pragma unroll
        for (int r = 0; r < 16; ++r) {
            int er = (r & 3) + 8 * (r >> 2) + 4 * hi;
            float keepl = wi ? acc1l[r] : acc0l[r];
            zfl[r] = keepl + scr[((wj * 2 + wi) * 32 + er) * 33 + l31];
        }
    }

    // quantize Z (16,8), split digits, store planes. e = 32wi + er.
    const int b_ = bh / NH, h = bh % NH;
    const int n = qt * 64 + 32 * wj + l31;
    const size_t rowoff = ((size_t)b_ * SEQ + n) * DIM + h * DH;
#pragma unroll
    for (int g = 0; g < 4; ++g) {
        int e0 = 32 * wi + 8 * g + 4 * hi;
        half4 ph, pl;
#pragma unroll
        for (int j = 0; j < 4; ++j) {
            int r = 4 * g + j;
            float zint = fmaf(2048.0f, zfh[r], zfl[r]);  // z_raw*65536
            float zq = rintf(zint * 0.00390625f);
            zq = fminf(fmaxf(zq, -32768.0f), 32767.0f);
            float zdh = rintf(zq * (1.0f / 2048.0f));
            ((_Float16*)&ph)[j] = (_Float16)zdh;
            ((_Float16*)&pl)[j] = (_Float16)(zq - 2048.0f * zdh);
        }
        *(half4*)(Zh16 + rowoff + e0) = ph;
        *(half4*)(Zl16 + rowoff + e0) = pl;
    }
}

// ---------------- K3: output projection, 32x32 MFMA, 64x64 tile, 3 blk/CU ---
__global__ __launch_bounds__(256, 4) void out_mfma(
    const _Float16* __restrict__ Zh, const _Float16* __restrict__ Zl,
    const _Float16* __restrict__ Wp16, const float* __restrict__ bp16,
    float* __restrict__ O)
{
    __shared__ __align__(16) _Float16 Ah[64 * 64];
    __shared__ __align__(16) _Float16 Al[64 * 64];
    __shared__ __align__(16) _Float16 Bs[64 * 64];
    const int t = threadIdx.x;
    const int w = t >> 6, lane = t & 63;
    const int l31 = lane & 31, hi = lane >> 5;
    const int wr = w >> 1;                // row strip (0/1)
    const int wc = w & 1;                 // col half (0/1)
    const int m0 = blockIdx.y * 64;
    const int col0 = blockIdx.x * 64;

    const int lr = lane >> 3;
    const int lg8 = ((lane & 7) ^ lr) * 8;

    floatx16 acch, accl;
#pragma unroll
    for (int r = 0; r < 16; ++r) { acch[r] = 0.f; accl[r] = 0.f; }

    for (int k0 = 0; k0 < DIM; k0 += 64) {
        __syncthreads();
        GLOAD16(Zh + (size_t)(m0 + 16 * w + lr) * DIM + k0 + lg8,
                &Ah[(2 * w) * 512]);
        GLOAD16(Zh + (size_t)(m0 + 16 * w + 8 + lr) * DIM + k0 + lg8,
                &Ah[(2 * w + 1) * 512]);
        GLOAD16(Zl + (size_t)(m0 + 16 * w + lr) * DIM + k0 + lg8,
                &Al[(2 * w) * 512]);
        GLOAD16(Zl + (size_t)(m0 + 16 * w + 8 + lr) * DIM + k0 + lg8,
                &Al[(2 * w + 1) * 512]);
        GLOAD16(Wp16 + (size_t)(col0 + 16 * w + lr) * DIM + k0 + lg8,
                &Bs[(2 * w) * 512]);
        GLOAD16(Wp16 + (size_t)(col0 + 16 * w + 8 + lr) * DIM + k0 + lg8,
                &Bs[(2 * w + 1) * 512]);
        __syncthreads();
#pragma unroll
        for (int i = 0; i < 4; ++i) {     // k-step of 16
            const int arow = 32 * wr + l31;
            const int brow = 32 * wc + l31;
            const int g = 2 * i + hi;
            half8 ah = *(const half8*)(&Ah[arow * 64 + ((g ^ (arow & 7)) << 3)]);
            half8 al = *(const half8*)(&Al[arow * 64 + ((g ^ (arow & 7)) << 3)]);
            half8 bf = *(const half8*)(&Bs[brow * 64 + ((g ^ (brow & 7)) << 3)]);
            acch = __builtin_amdgcn_mfma_f32_32x32x16_f16(ah, bf, acch, 0, 0, 0);
            accl = __builtin_amdgcn_mfma_f32_32x32x16_f16(al, bf, accl, 0, 0, 0);
        }
    }

    // epilogue: C rows = Z-token-rel er = (r&3)+8*(r>>2)+4*hi, cols = l31.
    {
        const int c = col0 + 32 * wc + l31;
        const float bb = bp16[c];
#pragma unroll
        for (int r = 0; r < 16; ++r) {
            int er = (r & 3) + 8 * (r >> 2) + 4 * hi;
            float y = fmaf(2048.0f, acch[r], accl[r]) + bb;
            float o = rintf(y * 0.00390625f) * 0.00390625f;
            O[(size_t)(m0 + 32 * wr + er) * DIM + c] = o;
        }
    }
}

extern "C" void kernel_launch(void* const* d_in, const int* in_sizes, int n_in,
                              void* d_out, int out_size, void* d_ws, size_t ws_size,
                              hipStream_t stream) {
    const float* q_in = (const float*)d_in[0];
    const float* wqkv = (const float*)d_in[1];
    const float* bqkv = (const float*)d_in[2];
    const float* wp   = (const float*)d_in[3];
    const float* bp   = (const float*)d_in[4];

    char* w = (char*)d_ws;
    _Float16* W16  = (_Float16*)w;  w += (size_t)QKVD * DIM * 2;
    _Float16* Wp16 = (_Float16*)w;  w += (size_t)DIM * DIM * 2;
    float* bq24    = (float*)w;     w += QKVD * 4;
    float* bp16    = (float*)w;     w += DIM * 4;
    _Float16* Xh   = (_Float16*)w;  w += (size_t)NTOK * DIM * 2;
    _Float16* Xl   = (_Float16*)w;  w += (size_t)NTOK * DIM * 2;
    _Float16* Q16  = (_Float16*)w;  w += (size_t)NBH * SEQ * DH * 2;
    _Float16* K16  = (_Float16*)w;  w += (size_t)NBH * SEQ * DH * 2;
    _Float16* Vt16 = (_Float16*)w;  w += (size_t)NBH * SEQ * DH * 2;
    _Float16* Zh16 = (_Float16*)w;  w += (size_t)NTOK * DIM * 2;
    _Float16* Zl16 = (_Float16*)w;  w += (size_t)NTOK * DIM * 2;
    (void)ws_size; (void)in_sizes; (void)n_in; (void)out_size;

    prep<<<dim3(NTOK * DIM / 4 / 256), 256, 0, stream>>>(
        q_in, wqkv, bqkv, wp, bp, Xh, Xl, W16, Wp16, bq24, bp16);
    qkv_mfma<<<dim3(NTOK / 64, QKVD / 128), 256, 0, stream>>>(
        Xh, Xl, W16, bq24, Q16, K16, Vt16);
    attention_mfma<<<dim3(NBH, SEQ / 64), 256, 0, stream>>>(Q16, K16, Vt16, Zh16, Zl16);
    out_mfma<<<dim3(DIM / 64, NTOK / 64), 256, 0, stream>>>(
        Zh16, Zl16, Wp16, bp16, (float*)d_out);
}